// Round 3
// baseline (226.127 us; speedup 1.0000x reference)
//
#include <hip/hip_runtime.h>
#include <hip/hip_bf16.h>
#include <stdint.h>

#define NROWS 32768
#define HDIM  1024
#define CNB   8
#define DCS   128
#define KCB   512
#define ROWS_PB 128

typedef short bf16x8 __attribute__((ext_vector_type(8)));
typedef float f32x4 __attribute__((ext_vector_type(4)));

__device__ __forceinline__ unsigned f2bfu(float x) {
  union { float f; unsigned u; } v; v.f = x;
  return (v.u + 0x7fffu + ((v.u >> 16) & 1u)) >> 16;
}
__device__ __forceinline__ float bfu2f(unsigned short b) {
  union { unsigned u; float f; } v; v.u = ((unsigned)b) << 16;
  return v.f;
}
__device__ __forceinline__ void gload_lds16(const void* g, void* l) {
  __builtin_amdgcn_global_load_lds(
      (const __attribute__((address_space(1))) uint32_t*)g,
      (__attribute__((address_space(3))) uint32_t*)l, 16, 0, 0);
}

// ---- prep: codesB[c] = bf16 XOR-swizzled 128KB image (4 chunks x 32KB, gl_lds-ready);
//      cn2[c][k] = ||code||^2; rcn = rsqrt(cn2); zero loss slot.
// image byte for (k,d): (k>>7)*32768 + (k&127)*256 + ((2d) ^ ((k&7)<<4))
__global__ __launch_bounds__(256) void prep_kernel(
    const float* __restrict__ codes, unsigned short* __restrict__ codesB,
    float* __restrict__ cn2, float* __restrict__ rcn, float* __restrict__ loss_slot) {
  const int c = blockIdx.y;
  const int k0 = blockIdx.x * 64;
  const int t = threadIdx.x;
  const int kl = t & 63;
  const int dq = t >> 6;
  const int k = k0 + kl;
  const float* src = codes + (size_t)c * DCS * KCB + k;
  char* dstbase = (char*)codesB + (size_t)c * 131072 + (size_t)(k >> 7) * 32768 + (k & 127) * 256;
  const unsigned swzk = (unsigned)(k & 7) << 4;
  float acc = 0.f;
#pragma unroll
  for (int g = 0; g < 4; ++g) {
    unsigned short pk[8];
#pragma unroll
    for (int j = 0; j < 8; ++j) {
      int d = dq * 32 + g * 8 + j;
      float v = src[(size_t)d * KCB];
      acc += v * v;
      pk[j] = (unsigned short)f2bfu(v);
    }
    unsigned d2 = (unsigned)((dq * 32 + g * 8) * 2);
    *(uint4*)(dstbase + (d2 ^ swzk)) = *(const uint4*)pk;
  }
  __shared__ float red[256];
  red[t] = acc;
  __syncthreads();
  if (t < 64) {
    float s = red[t] + red[t + 64] + red[t + 128] + red[t + 192];
    cn2[c * KCB + k0 + t] = s;
    rcn[c * KCB + k0 + t] = rsqrtf(s);
  }
  if (blockIdx.x == 0 && c == 0 && t == 0) *loss_slot = 0.f;
}

// ---- main: 128 rows x 1 codebook per block; 8 waves x 16 rows.
// MFMA: A = codes tile (16k x 32d from LDS), B = h rows -> D[row=code, col=h-row].
__global__ __launch_bounds__(512, 4) void vq_kernel(
    const float* __restrict__ hidden, const float* __restrict__ gumbel,
    const unsigned short* __restrict__ codesB, const float* __restrict__ cn2g,
    const float* __restrict__ rcn, float* __restrict__ out, float* __restrict__ loss_slot) {
  const int c = blockIdx.y;
  const int nb = blockIdx.x * ROWS_PB;
  const int tid = threadIdx.x;
  const int w = tid >> 6;
  const int l = tid & 63;
  const int l15 = l & 15;
  const int l4 = l >> 4;

  __shared__ char ldsB[32768];   // one 32KB chunk: [k_local 128][d 128] bf16, XOR-swizzled
  __shared__ float wloss[8];

  const char* cbase = (const char*)codesB + (size_t)c * 131072;

  // prologue stage of chunk 0 (overlaps h load/norm below)
#pragma unroll
  for (int i = 0; i < 4; ++i)
    gload_lds16(cbase + i * 8192 + tid * 16, ldsB + i * 8192 + w * 1024);

  // --- h rows: per lane row = nb + w*16 + l15, d = s*32 + l4*8 + j
  const int nrow = nb + w * 16 + l15;
  const float* hp = hidden + (size_t)nrow * HDIM + c * DCS + l4 * 8;
  float hv[4][8];
  float hn2 = 0.f;
#pragma unroll
  for (int s = 0; s < 4; ++s) {
    f32x4 p0 = *(const f32x4*)(hp + s * 32);
    f32x4 p1 = *(const f32x4*)(hp + s * 32 + 4);
#pragma unroll
    for (int j = 0; j < 4; ++j) { hv[s][j] = p0[j]; hv[s][4 + j] = p1[j]; }
#pragma unroll
    for (int j = 0; j < 8; ++j) hn2 += hv[s][j] * hv[s][j];
  }
  hn2 += __shfl_xor(hn2, 16);
  hn2 += __shfl_xor(hn2, 32);
  const float hnorm = sqrtf(hn2);
  const float rh = hnorm > 0.f ? 1.0f / hnorm : 0.f;
  bf16x8 afr[4];
#pragma unroll
  for (int s = 0; s < 4; ++s)
#pragma unroll
    for (int j = 0; j < 8; ++j) afr[s][j] = (short)f2bfu(hv[s][j] * rh);

  const float* gbase = gumbel + ((size_t)nrow * CNB + c) * KCB + l4 * 4;
  const float* rbase = rcn + c * KCB + l4 * 4;
  const unsigned swz = (unsigned)(l15 & 7) << 4;

  float bs = -3.4e38f, ba = 0.f;
  int bk = 0;

  __syncthreads();   // chunk 0 staged

#pragma unroll 1
  for (int kc = 0; kc < KCB; kc += 128) {
    // --- MFMA over current chunk
    f32x4 acc[8];
#pragma unroll
    for (int t = 0; t < 8; ++t) acc[t] = (f32x4){0.f, 0.f, 0.f, 0.f};
#pragma unroll
    for (int t = 0; t < 8; ++t) {
      const unsigned rowbase = (unsigned)((t * 16 + l15) * 256);
#pragma unroll
      for (int s = 0; s < 4; ++s) {
        bf16x8 bfr = *(const bf16x8*)(ldsB + rowbase + (((unsigned)(s * 64 + l4 * 16)) ^ swz));
        acc[t] = __builtin_amdgcn_mfma_f32_16x16x32_bf16(bfr, afr[s], acc[t], 0, 0, 0);
      }
    }
    __syncthreads();   // all waves done reading this chunk

    // --- issue next-chunk stage; its latency hides under the score phase
    if (kc + 128 < KCB) {
      const char* src = cbase + (size_t)((kc >> 7) + 1) * 32768;
#pragma unroll
      for (int i = 0; i < 4; ++i)
        gload_lds16(src + i * 8192 + tid * 16, ldsB + i * 8192 + w * 1024);
    }

    // --- scores + per-lane argmax (k = kc + t*16 + l4*4 + r, all for h-row l15)
#pragma unroll
    for (int t = 0; t < 8; ++t) {
      f32x4 g = *(const f32x4*)(gbase + kc + t * 16);
      f32x4 rc = *(const f32x4*)(rbase + kc + t * 16);
#pragma unroll
      for (int r = 0; r < 4; ++r) {
        const int kf = kc + t * 16 + l4 * 4 + r;
        float sc = fmaf(acc[t][r], rc[r], g[r]);
        if (sc > bs) { bs = sc; bk = kf; ba = acc[t][r]; }
      }
    }
    __syncthreads();   // next chunk staged (vmcnt drain at barrier)
  }

  // --- cross-lane argmax over the 4 l4 replicas of each h-row
#pragma unroll
  for (int m = 16; m <= 32; m <<= 1) {
    float os = __shfl_xor(bs, m);
    int ok = __shfl_xor(bk, m);
    float oa = __shfl_xor(ba, m);
    if (os > bs || (os == bs && ok < bk)) { bs = os; bk = ok; ba = oa; }
  }

  // --- epilogue: nh row copy (bf16->f32 from codesB), loss via ||c||^2+||h||^2-2*dot
  const float c2 = cn2g[c * KCB + bk];
  const float arg = c2 + hn2 - 2.f * (ba * hnorm);
  float lsum = (l4 == 0) ? sqrtf(fmaxf(arg, 0.f)) : 0.f;

  const char* cb = cbase + (size_t)(bk >> 7) * 32768 + (bk & 127) * 256;
  const unsigned swzk = (unsigned)(bk & 7) << 4;
  float* op = out + (size_t)nrow * HDIM + c * DCS + l4 * 32;
#pragma unroll
  for (int j = 0; j < 4; ++j) {
    unsigned d2 = (unsigned)((l4 * 32 + j * 8) * 2);
    bf16x8 cv = *(const bf16x8*)(cb + (d2 ^ swzk));
    f32x4 o0, o1;
#pragma unroll
    for (int e = 0; e < 4; ++e) {
      o0[e] = bfu2f((unsigned short)cv[e]);
      o1[e] = bfu2f((unsigned short)cv[4 + e]);
    }
    *(f32x4*)(op + j * 8) = o0;
    *(f32x4*)(op + j * 8 + 4) = o1;
  }

#pragma unroll
  for (int m = 1; m <= 32; m <<= 1) lsum += __shfl_xor(lsum, m);
  if (l == 0) wloss[w] = lsum;
  __syncthreads();
  if (tid == 0) {
    float tot = 0.f;
#pragma unroll
    for (int i = 0; i < 8; ++i) tot += wloss[i];
    atomicAdd(loss_slot, tot * 1.2f);
  }
}

extern "C" void kernel_launch(void* const* d_in, const int* in_sizes, int n_in,
                              void* d_out, int out_size, void* d_ws, size_t ws_size,
                              hipStream_t stream) {
  const float* hidden = (const float*)d_in[0];
  const float* codes  = (const float*)d_in[1];
  const float* gumbel = (const float*)d_in[2];
  float* out = (float*)d_out;
  unsigned short* codesB = (unsigned short*)d_ws;          // 1 MB (8 x 128KB images)
  float* cn2 = (float*)((char*)d_ws + (size_t)CNB * 131072);  // 16 KB
  float* rcn = cn2 + CNB * KCB;                            // 16 KB
  float* loss_slot = out + (size_t)NROWS * HDIM;

  prep_kernel<<<dim3(8, CNB), 256, 0, stream>>>(codes, codesB, cn2, rcn, loss_slot);
  vq_kernel<<<dim3(NROWS / ROWS_PB, CNB), 512, 0, stream>>>(hidden, gumbel, codesB, cn2, rcn, out, loss_slot);
}

// Round 4
// 225.582 us; speedup vs baseline: 1.0024x; 1.0024x over previous
//
#include <hip/hip_runtime.h>
#include <hip/hip_bf16.h>
#include <stdint.h>

#define NROWS 32768
#define HDIM  1024
#define CNB   8
#define DCS   128
#define KCB   512
#define ROWS_PB 128

typedef short bf16x8 __attribute__((ext_vector_type(8)));
typedef float f32x4 __attribute__((ext_vector_type(4)));

__device__ __forceinline__ unsigned f2bfu(float x) {
  union { float f; unsigned u; } v; v.f = x;
  return (v.u + 0x7fffu + ((v.u >> 16) & 1u)) >> 16;
}
__device__ __forceinline__ float bfu2f(unsigned short b) {
  union { unsigned u; float f; } v; v.u = ((unsigned)b) << 16;
  return v.f;
}
__device__ __forceinline__ void gload_lds16(const void* g, void* l) {
  __builtin_amdgcn_global_load_lds(
      (const __attribute__((address_space(1))) uint32_t*)g,
      (__attribute__((address_space(3))) uint32_t*)l, 16, 0, 0);
}

// ---- prep: codesB[c] = bf16 XOR-swizzled 128KB image (4 chunks x 32KB, gl_lds-ready);
//      cn2[c][k] = ||code||^2; rcn = rsqrt(cn2); zero loss slot.
// image byte for (k,d): (k>>7)*32768 + (k&127)*256 + ((2d) ^ ((k&7)<<4))
__global__ __launch_bounds__(256) void prep_kernel(
    const float* __restrict__ codes, unsigned short* __restrict__ codesB,
    float* __restrict__ cn2, float* __restrict__ rcn, float* __restrict__ loss_slot) {
  const int c = blockIdx.y;
  const int k0 = blockIdx.x * 64;
  const int t = threadIdx.x;
  const int kl = t & 63;
  const int dq = t >> 6;
  const int k = k0 + kl;
  const float* src = codes + (size_t)c * DCS * KCB + k;
  char* dstbase = (char*)codesB + (size_t)c * 131072 + (size_t)(k >> 7) * 32768 + (k & 127) * 256;
  const unsigned swzk = (unsigned)(k & 7) << 4;
  float acc = 0.f;
#pragma unroll
  for (int g = 0; g < 4; ++g) {
    unsigned short pk[8];
#pragma unroll
    for (int j = 0; j < 8; ++j) {
      int d = dq * 32 + g * 8 + j;
      float v = src[(size_t)d * KCB];
      acc += v * v;
      pk[j] = (unsigned short)f2bfu(v);
    }
    unsigned d2 = (unsigned)((dq * 32 + g * 8) * 2);
    *(uint4*)(dstbase + (d2 ^ swzk)) = *(const uint4*)pk;
  }
  __shared__ float red[256];
  red[t] = acc;
  __syncthreads();
  if (t < 64) {
    float s = red[t] + red[t + 64] + red[t + 128] + red[t + 192];
    cn2[c * KCB + k0 + t] = s;
    rcn[c * KCB + k0 + t] = rsqrtf(s);
  }
  if (blockIdx.x == 0 && c == 0 && t == 0) *loss_slot = 0.f;
}

// ---- main: 128 rows x 1 codebook per block; 8 waves x 16 rows.
// MFMA: A = codes tile (16k x 32d from LDS), B = h rows -> D[row=code, col=h-row].
__global__ __launch_bounds__(512, 4) void vq_kernel(
    const float* __restrict__ hidden, const float* __restrict__ gumbel,
    const unsigned short* __restrict__ codesB, const float* __restrict__ cn2g,
    const float* __restrict__ rcn, float* __restrict__ out, float* __restrict__ loss_slot) {
  const int c = blockIdx.y;
  const int nb = blockIdx.x * ROWS_PB;
  const int tid = threadIdx.x;
  const int w = tid >> 6;
  const int l = tid & 63;
  const int l15 = l & 15;
  const int l4 = l >> 4;

  __shared__ char ldsB[32768];   // one 32KB chunk: [k_local 128][d 128] bf16, XOR-swizzled
  __shared__ float wloss[8];

  const char* cbase = (const char*)codesB + (size_t)c * 131072;

  // prologue stage of chunk 0 (overlaps h load/norm below)
#pragma unroll
  for (int i = 0; i < 4; ++i)
    gload_lds16(cbase + i * 8192 + tid * 16, ldsB + i * 8192 + w * 1024);

  // --- h rows: per lane row = nb + w*16 + l15, d = s*32 + l4*8 + j
  const int nrow = nb + w * 16 + l15;
  const float* hp = hidden + (size_t)nrow * HDIM + c * DCS + l4 * 8;
  float hv[4][8];
  float hn2 = 0.f;
#pragma unroll
  for (int s = 0; s < 4; ++s) {
    f32x4 p0 = *(const f32x4*)(hp + s * 32);
    f32x4 p1 = *(const f32x4*)(hp + s * 32 + 4);
#pragma unroll
    for (int j = 0; j < 4; ++j) { hv[s][j] = p0[j]; hv[s][4 + j] = p1[j]; }
#pragma unroll
    for (int j = 0; j < 8; ++j) hn2 += hv[s][j] * hv[s][j];
  }
  hn2 += __shfl_xor(hn2, 16);
  hn2 += __shfl_xor(hn2, 32);
  const float hnorm = sqrtf(hn2);
  const float rh = hnorm > 0.f ? 1.0f / hnorm : 0.f;
  bf16x8 afr[4];
#pragma unroll
  for (int s = 0; s < 4; ++s)
#pragma unroll
    for (int j = 0; j < 8; ++j) afr[s][j] = (short)f2bfu(hv[s][j] * rh);

  const float* gbase = gumbel + ((size_t)nrow * CNB + c) * KCB + l4 * 4;
  const float* rbase = rcn + c * KCB + l4 * 4;
  const unsigned swz = (unsigned)(l15 & 7) << 4;

  float bs = -3.4e38f, ba = 0.f;
  int bk = 0;

  __syncthreads();   // chunk 0 staged

#pragma unroll 1
  for (int kc = 0; kc < KCB; kc += 128) {
    // --- MFMA over current chunk
    f32x4 acc[8];
#pragma unroll
    for (int t = 0; t < 8; ++t) acc[t] = (f32x4){0.f, 0.f, 0.f, 0.f};
#pragma unroll
    for (int t = 0; t < 8; ++t) {
      const unsigned rowbase = (unsigned)((t * 16 + l15) * 256);
#pragma unroll
      for (int s = 0; s < 4; ++s) {
        bf16x8 bfr = *(const bf16x8*)(ldsB + rowbase + (((unsigned)(s * 64 + l4 * 16)) ^ swz));
        acc[t] = __builtin_amdgcn_mfma_f32_16x16x32_bf16(bfr, afr[s], acc[t], 0, 0, 0);
      }
    }
    __syncthreads();   // all waves done reading this chunk

    // --- issue next-chunk stage; its latency hides under the score phase
    if (kc + 128 < KCB) {
      const char* src = cbase + (size_t)((kc >> 7) + 1) * 32768;
#pragma unroll
      for (int i = 0; i < 4; ++i)
        gload_lds16(src + i * 8192 + tid * 16, ldsB + i * 8192 + w * 1024);
    }

    // --- scores + per-lane argmax (k = kc + t*16 + l4*4 + r, all for h-row l15)
#pragma unroll
    for (int t = 0; t < 8; ++t) {
      f32x4 g = *(const f32x4*)(gbase + kc + t * 16);
      f32x4 rc = *(const f32x4*)(rbase + kc + t * 16);
#pragma unroll
      for (int r = 0; r < 4; ++r) {
        const int kf = kc + t * 16 + l4 * 4 + r;
        float sc = fmaf(acc[t][r], rc[r], g[r]);
        if (sc > bs) { bs = sc; bk = kf; ba = acc[t][r]; }
      }
    }
    __syncthreads();   // next chunk staged (vmcnt drain at barrier)
  }

  // --- cross-lane argmax over the 4 l4 replicas of each h-row
#pragma unroll
  for (int m = 16; m <= 32; m <<= 1) {
    float os = __shfl_xor(bs, m);
    int ok = __shfl_xor(bk, m);
    float oa = __shfl_xor(ba, m);
    if (os > bs || (os == bs && ok < bk)) { bs = os; bk = ok; ba = oa; }
  }

  // --- epilogue: nh row copy (bf16->f32 from codesB), loss via ||c||^2+||h||^2-2*dot
  const float c2 = cn2g[c * KCB + bk];
  const float arg = c2 + hn2 - 2.f * (ba * hnorm);
  float lsum = (l4 == 0) ? sqrtf(fmaxf(arg, 0.f)) : 0.f;

  const char* cb = cbase + (size_t)(bk >> 7) * 32768 + (bk & 127) * 256;
  const unsigned swzk = (unsigned)(bk & 7) << 4;
  float* op = out + (size_t)nrow * HDIM + c * DCS + l4 * 32;
#pragma unroll
  for (int j = 0; j < 4; ++j) {
    unsigned d2 = (unsigned)((l4 * 32 + j * 8) * 2);
    bf16x8 cv = *(const bf16x8*)(cb + (d2 ^ swzk));
    f32x4 o0, o1;
#pragma unroll
    for (int e = 0; e < 4; ++e) {
      o0[e] = bfu2f((unsigned short)cv[e]);
      o1[e] = bfu2f((unsigned short)cv[4 + e]);
    }
    *(f32x4*)(op + j * 8) = o0;
    *(f32x4*)(op + j * 8 + 4) = o1;
  }

#pragma unroll
  for (int m = 1; m <= 32; m <<= 1) lsum += __shfl_xor(lsum, m);
  if (l == 0) wloss[w] = lsum;
  __syncthreads();
  if (tid == 0) {
    float tot = 0.f;
#pragma unroll
    for (int i = 0; i < 8; ++i) tot += wloss[i];
    atomicAdd(loss_slot, tot * 1.2f);
  }
}

extern "C" void kernel_launch(void* const* d_in, const int* in_sizes, int n_in,
                              void* d_out, int out_size, void* d_ws, size_t ws_size,
                              hipStream_t stream) {
  const float* hidden = (const float*)d_in[0];
  const float* codes  = (const float*)d_in[1];
  const float* gumbel = (const float*)d_in[2];
  float* out = (float*)d_out;
  unsigned short* codesB = (unsigned short*)d_ws;          // 1 MB (8 x 128KB images)
  float* cn2 = (float*)((char*)d_ws + (size_t)CNB * 131072);  // 16 KB
  float* rcn = cn2 + CNB * KCB;                            // 16 KB
  float* loss_slot = out + (size_t)NROWS * HDIM;

  prep_kernel<<<dim3(8, CNB), 256, 0, stream>>>(codes, codesB, cn2, rcn, loss_slot);
  vq_kernel<<<dim3(NROWS / ROWS_PB, CNB), 512, 0, stream>>>(hidden, gumbel, codesB, cn2, rcn, out, loss_slot);
}